// Round 9
// baseline (140.744 us; speedup 1.0000x reference)
//
#include <hip/hip_runtime.h>
#include <hip/hip_cooperative_groups.h>
#include <math.h>

namespace cg = cooperative_groups;

#define EPS 1e-5f

constexpr int Bc = 16, Cc = 32, Pc = 8, HIDc = 256, OUTc = 128;
constexpr int NBINS = 4096;
constexpr float NPC_INV = 1.0f / 2097152.0f;

typedef float fx4 __attribute__((ext_vector_type(4)));

// ws layout (floats): [0,4096) max | [4096,8192) min | [8192,12288) sum | [12288,16384) sumsq

// One cooperative kernel. 256 blocks x 512 threads (1 block/CU guaranteed by
// __launch_bounds__(512,2) => VGPR<=256).
// Phase 1: all blocks stream x (16 bins/block, 2 bins/wave, no block syncs).
//          Blocks 0..15 additionally hold their w_hh register tile, loaded at kernel
//          top, so the 256KB/block weight fetch overlaps the 41us stream.
// grid.sync(), then blocks 0..15 run the RNN tail (r8 structure).
__global__ __launch_bounds__(512, 2) void fused(const float* __restrict__ x,
                                                float* __restrict__ ws,
                                                const float* __restrict__ bn_gamma,
                                                const float* __restrict__ bn_beta,
                                                const float* __restrict__ w_ih,
                                                const float* __restrict__ b_ih,
                                                const float* __restrict__ w_hh,
                                                const float* __restrict__ b_hh,
                                                const float* __restrict__ w_out,
                                                const float* __restrict__ b_out,
                                                const float* __restrict__ ln_gamma,
                                                const float* __restrict__ ln_beta,
                                                float* __restrict__ out) {
    const int bid = blockIdx.x;
    const int t = threadIdx.x;                 // 512 threads
    const int og = t >> 3, kg = t & 7;
    const int wid = t >> 6, lane = t & 63;

    __shared__ float scale_s[Cc], shift_s[Cc];
    __shared__ float pA[2][Cc], pB[2][Cc];
    __shared__ __align__(16) float pooled[Pc][Cc];
    __shared__ __align__(16) float u[Pc][HIDc];
    __shared__ __align__(16) float hxs[2][288];   // 8 groups * 36 words, double-buffered
    __shared__ __align__(16) float o[OUTc];
    __shared__ float red2[2];

    // ---- k2 blocks: issue w_hh tile loads NOW; they drain under the phase-1 stream ----
    float4 w4[4][8];
    if (bid < Bc) {
#pragma unroll
        for (int r = 0; r < 4; ++r) {
            const float4* wr = reinterpret_cast<const float4*>(w_hh + (4 * og + r) * HIDc + 32 * kg);
#pragma unroll
            for (int e = 0; e < 8; ++e) w4[r][e] = wr[e];
        }
    }

    // ---- Phase 1: per-wave bin stats (no block-level syncs) ----
#pragma unroll
    for (int i = 0; i < 2; ++i) {
        const int bin = bid * 16 + wid * 2 + i;
        const fx4* px = reinterpret_cast<const fx4*>(x) + ((size_t)bin << 12) + lane;
        float vmax = -INFINITY, vmin = INFINITY, s = 0.f, ss = 0.f;
        for (int jj = 0; jj < 8; ++jj) {
#pragma unroll
            for (int j = 0; j < 8; ++j) {
                fx4 v = __builtin_nontemporal_load(&px[(jj * 8 + j) * 64]);
                vmax = fmaxf(vmax, fmaxf(fmaxf(v.x, v.y), fmaxf(v.z, v.w)));
                vmin = fminf(vmin, fminf(fminf(v.x, v.y), fminf(v.z, v.w)));
                s += (v.x + v.y) + (v.z + v.w);
                ss = fmaf(v.x, v.x, ss); ss = fmaf(v.y, v.y, ss);
                ss = fmaf(v.z, v.z, ss); ss = fmaf(v.w, v.w, ss);
            }
        }
#pragma unroll
        for (int off = 1; off < 64; off <<= 1) {
            vmax = fmaxf(vmax, __shfl_xor(vmax, off));
            vmin = fminf(vmin, __shfl_xor(vmin, off));
            s += __shfl_xor(s, off);
            ss += __shfl_xor(ss, off);
        }
        if (lane == 0) {
            ws[bin]             = vmax;
            ws[NBINS + bin]     = vmin;
            ws[2 * NBINS + bin] = s;
            ws[3 * NBINS + bin] = ss;
        }
    }

    // ---- All bins done everywhere ----
    cg::this_grid().sync();
    if (bid >= Bc) return;
    const int b = bid;

    // ---- Stage A: channel stats, fully coalesced (c constant per thread) ----
    {
        const float* sums = ws + 2 * NBINS;
        const float* sqs  = ws + 3 * NBINS;
        float s = 0.f, ss = 0.f;
#pragma unroll
        for (int j = 0; j < 8; ++j) {          // flat = t + 512j: c=(t>>3)&31 invariant
            s  += sums[t + 512 * j];
            ss += sqs[t + 512 * j];
        }
#pragma unroll
        for (int off = 1; off < 8; off <<= 1) {
            s  += __shfl_xor(s, off);
            ss += __shfl_xor(ss, off);
        }
        if ((t & 7) == 0) {
            const int c = (t >> 3) & 31, half = t >> 8;
            pA[half][c] = s;
            pB[half][c] = ss;
        }
    }
    __syncthreads();
    if (t < Cc) {
        const float s = pA[0][t] + pA[1][t], ss = pB[0][t] + pB[1][t];
        const float mean = s * NPC_INV;
        const float var  = ss * NPC_INV - mean * mean;
        const float sc   = bn_gamma[t] * rsqrtf(var + EPS);
        scale_s[t] = sc;
        shift_s[t] = bn_beta[t] - mean * sc;
    }
    __syncthreads();

    // ---- Stage B: pooled (coalesced: bid = b*256 + t) ----
    if (t < Pc * Cc) {
        const int c = t >> 3, p = t & 7;
        const int bin = b * 256 + t;
        const float sc = scale_s[c];
        const float xm = (sc >= 0.f) ? ws[bin] : ws[NBINS + bin];
        pooled[p][c] = fmaxf(fmaf(sc, xm, shift_s[c]), 0.f);
    }
    __syncthreads();

    // ---- Stage C: u[p][h], 512 threads = 256 h x 2 p-halves (4 p each) ----
    {
        const int h = t & 255, pq = t >> 8;
        const float4* wi = reinterpret_cast<const float4*>(w_ih) + h * (Cc / 4);
        float4 wiv[8];
#pragma unroll
        for (int e = 0; e < 8; ++e) wiv[e] = wi[e];
        const float bias = b_ih[h] + b_hh[h];
        float u0 = 0.f;
#pragma unroll
        for (int pp = 0; pp < 4; ++pp) {
            const int p = pq * 4 + pp;
            const float4* pl = reinterpret_cast<const float4*>(&pooled[p][0]);
            float a0 = bias, a1 = 0.f, a2 = 0.f, a3 = 0.f;
#pragma unroll
            for (int e = 0; e < 8; ++e) {
                float4 pv = pl[e];
                a0 = fmaf(pv.x, wiv[e].x, a0);
                a1 = fmaf(pv.y, wiv[e].y, a1);
                a2 = fmaf(pv.z, wiv[e].z, a2);
                a3 = fmaf(pv.w, wiv[e].w, a3);
            }
            const float uv = (a0 + a1) + (a2 + a3);
            u[p][h] = uv;
            if (pp == 0) u0 = uv;
        }
        if (pq == 0) hxs[0][(h >> 5) * 36 + (h & 31)] = fmaxf(u0, 0.f);
    }
    __syncthreads();

    // ---- Stage D: 7 recurrent steps, one barrier each (w4 already resident) ----
    int cur = 0;
    for (int step = 1; step < Pc; ++step) {
        float4 h4[8];
        const float4* hp = reinterpret_cast<const float4*>(&hxs[cur][kg * 36]);
#pragma unroll
        for (int e = 0; e < 8; ++e) h4[e] = hp[e];
        float acc[4];
#pragma unroll
        for (int r = 0; r < 4; ++r) {
            float a0 = 0.f, a1 = 0.f, a2 = 0.f, a3 = 0.f;
#pragma unroll
            for (int e = 0; e < 8; ++e) {
                float4 wv = w4[r][e], hv = h4[e];
                a0 = fmaf(hv.x, wv.x, a0);
                a1 = fmaf(hv.y, wv.y, a1);
                a2 = fmaf(hv.z, wv.z, a2);
                a3 = fmaf(hv.w, wv.w, a3);
            }
            acc[r] = (a0 + a1) + (a2 + a3);
        }
#pragma unroll
        for (int off = 1; off < 8; off <<= 1) {
#pragma unroll
            for (int r = 0; r < 4; ++r) acc[r] += __shfl_xor(acc[r], off);
        }
        if (kg == 0) {
#pragma unroll
            for (int r = 0; r < 4; ++r) {
                const int h = 4 * og + r;
                const float v = u[step][h] + acc[r];
                hxs[cur ^ 1][(h >> 5) * 36 + (h & 31)] = fmaxf(v, 0.f);
            }
        }
        __syncthreads();
        cur ^= 1;
    }

    // ---- Stage E: out = hx @ w_out^T + b_out (4 threads/output, 64-k slices) ----
    {
        const int oi = t >> 2, seg = t & 3;
        const float4* wo = reinterpret_cast<const float4*>(w_out + oi * HIDc + seg * 64);
        float a0 = (seg == 0) ? b_out[oi] : 0.f, a1 = 0.f, a2 = 0.f, a3 = 0.f;
#pragma unroll
        for (int e = 0; e < 16; ++e) {
            const int k = seg * 64 + e * 4;
            const float4 hv = *reinterpret_cast<const float4*>(&hxs[1][(k >> 5) * 36 + (k & 31)]);
            const float4 wv = wo[e];
            a0 = fmaf(hv.x, wv.x, a0);
            a1 = fmaf(hv.y, wv.y, a1);
            a2 = fmaf(hv.z, wv.z, a2);
            a3 = fmaf(hv.w, wv.w, a3);
        }
        float s = (a0 + a1) + (a2 + a3);
        s += __shfl_xor(s, 1);
        s += __shfl_xor(s, 2);
        if (seg == 0) o[oi] = s;
    }
    __syncthreads();

    // ---- LayerNorm over 128 ----
    if (t < 64) {
        const float x0 = o[t], x1 = o[t + 64];
        float s = x0 + x1, ss = x0 * x0 + x1 * x1;
#pragma unroll
        for (int off = 1; off < 64; off <<= 1) {
            s  += __shfl_xor(s, off);
            ss += __shfl_xor(ss, off);
        }
        if (t == 0) { red2[0] = s; red2[1] = ss; }
    }
    __syncthreads();
    if (t < OUTc) {
        const float mu  = red2[0] * (1.0f / OUTc);
        const float var = red2[1] * (1.0f / OUTc) - mu * mu;
        const float rs  = rsqrtf(var + EPS);
        out[b * OUTc + t] = (o[t] - mu) * rs * ln_gamma[t] + ln_beta[t];
    }
}

extern "C" void kernel_launch(void* const* d_in, const int* in_sizes, int n_in,
                              void* d_out, int out_size, void* d_ws, size_t ws_size,
                              hipStream_t stream) {
    const float* x        = (const float*)d_in[0];
    const float* bn_gamma = (const float*)d_in[1];
    const float* bn_beta  = (const float*)d_in[2];
    const float* w_ih     = (const float*)d_in[3];
    const float* b_ih     = (const float*)d_in[4];
    const float* w_hh     = (const float*)d_in[5];
    const float* b_hh     = (const float*)d_in[6];
    const float* w_out    = (const float*)d_in[7];
    const float* b_out    = (const float*)d_in[8];
    const float* ln_gamma = (const float*)d_in[9];
    const float* ln_beta  = (const float*)d_in[10];
    float* out = (float*)d_out;
    float* ws  = (float*)d_ws;

    void* args[] = {(void*)&x, (void*)&ws, (void*)&bn_gamma, (void*)&bn_beta,
                    (void*)&w_ih, (void*)&b_ih, (void*)&w_hh, (void*)&b_hh,
                    (void*)&w_out, (void*)&b_out, (void*)&ln_gamma, (void*)&ln_beta,
                    (void*)&out};
    hipLaunchCooperativeKernel((void*)fused, dim3(256), dim3(512), args, 0, stream);
}

// Round 10
// 104.455 us; speedup vs baseline: 1.3474x; 1.3474x over previous
//
#include <hip/hip_runtime.h>
#include <math.h>

#define EPS 1e-5f

constexpr int Bc = 16, Cc = 32, Pc = 8, HIDc = 256, OUTc = 128;
constexpr int NBINS = 4096;
constexpr float NPC_INV = 1.0f / 2097152.0f;

typedef float fx4 __attribute__((ext_vector_type(4)));

// ws layout (floats): [0,4096) max | [4096,8192) min | [8192,12288) sum | [12288,16384) sumsq

// ---------------- Kernel 1: byte-identical to r8 (41 us = 6.5 TB/s, at read ceiling) ----------------
__global__ __launch_bounds__(256) void k1_stats(const float* __restrict__ x,
                                                float* __restrict__ ws) {
    const int bid = blockIdx.x;
    const int t = threadIdx.x;
    const fx4* px = reinterpret_cast<const fx4*>(x) + ((size_t)bid << 12);

    float vmax = -INFINITY, vmin = INFINITY, s = 0.f, ss = 0.f;
#pragma unroll
    for (int j = 0; j < 16; ++j) {
        fx4 v = __builtin_nontemporal_load(&px[j * 256 + t]);
        vmax = fmaxf(vmax, fmaxf(fmaxf(v.x, v.y), fmaxf(v.z, v.w)));
        vmin = fminf(vmin, fminf(fminf(v.x, v.y), fminf(v.z, v.w)));
        s += (v.x + v.y) + (v.z + v.w);
        ss = fmaf(v.x, v.x, ss); ss = fmaf(v.y, v.y, ss);
        ss = fmaf(v.z, v.z, ss); ss = fmaf(v.w, v.w, ss);
    }
#pragma unroll
    for (int off = 1; off < 64; off <<= 1) {
        vmax = fmaxf(vmax, __shfl_xor(vmax, off));
        vmin = fminf(vmin, __shfl_xor(vmin, off));
        s += __shfl_xor(s, off);
        ss += __shfl_xor(ss, off);
    }
    __shared__ float r[4][4];
    const int wid = t >> 6;
    if ((t & 63) == 0) { r[wid][0] = vmax; r[wid][1] = vmin; r[wid][2] = s; r[wid][3] = ss; }
    __syncthreads();
    if (t == 0) {
        vmax = fmaxf(fmaxf(r[0][0], r[1][0]), fmaxf(r[2][0], r[3][0]));
        vmin = fminf(fminf(r[0][1], r[1][1]), fminf(r[2][1], r[3][1]));
        s  = (r[0][2] + r[1][2]) + (r[2][2] + r[3][2]);
        ss = (r[0][3] + r[1][3]) + (r[2][3] + r[3][3]);
        ws[bid]             = vmax;
        ws[NBINS + bid]     = vmin;
        ws[2 * NBINS + bid] = s;
        ws[3 * NBINS + bid] = ss;
    }
}

// ---------------- Kernel 2: byte-identical to r8. ATTRIBUTION: launched 3x ----------------
__global__ __launch_bounds__(512, 2) void k2_rnn(const float* __restrict__ ws,
                                                 const float* __restrict__ bn_gamma,
                                                 const float* __restrict__ bn_beta,
                                                 const float* __restrict__ w_ih,
                                                 const float* __restrict__ b_ih,
                                                 const float* __restrict__ w_hh,
                                                 const float* __restrict__ b_hh,
                                                 const float* __restrict__ w_out,
                                                 const float* __restrict__ b_out,
                                                 const float* __restrict__ ln_gamma,
                                                 const float* __restrict__ ln_beta,
                                                 float* __restrict__ out) {
    const int b = blockIdx.x;
    const int t = threadIdx.x;                 // 512 threads
    const int og = t >> 3, kg = t & 7;

    __shared__ float scale_s[Cc], shift_s[Cc];
    __shared__ float pA[2][Cc], pB[2][Cc];
    __shared__ __align__(16) float pooled[Pc][Cc];
    __shared__ __align__(16) float u[Pc][HIDc];
    __shared__ __align__(16) float hxs[2][288];
    __shared__ __align__(16) float o[OUTc];
    __shared__ float red2[2];

    // ---- Stage A: channel stats, coalesced ----
    {
        const float* sums = ws + 2 * NBINS;
        const float* sqs  = ws + 3 * NBINS;
        float s = 0.f, ss = 0.f;
#pragma unroll
        for (int j = 0; j < 8; ++j) {
            s  += sums[t + 512 * j];
            ss += sqs[t + 512 * j];
        }
#pragma unroll
        for (int off = 1; off < 8; off <<= 1) {
            s  += __shfl_xor(s, off);
            ss += __shfl_xor(ss, off);
        }
        if ((t & 7) == 0) {
            const int c = (t >> 3) & 31, half = t >> 8;
            pA[half][c] = s;
            pB[half][c] = ss;
        }
    }

    // ---- Issue w_hh tile loads ----
    float4 w4[4][8];
#pragma unroll
    for (int r = 0; r < 4; ++r) {
        const float4* wr = reinterpret_cast<const float4*>(w_hh + (4 * og + r) * HIDc + 32 * kg);
#pragma unroll
        for (int e = 0; e < 8; ++e) w4[r][e] = wr[e];
    }

    __syncthreads();
    if (t < Cc) {
        const float s = pA[0][t] + pA[1][t], ss = pB[0][t] + pB[1][t];
        const float mean = s * NPC_INV;
        const float var  = ss * NPC_INV - mean * mean;
        const float sc   = bn_gamma[t] * rsqrtf(var + EPS);
        scale_s[t] = sc;
        shift_s[t] = bn_beta[t] - mean * sc;
    }
    __syncthreads();

    // ---- Stage B ----
    if (t < Pc * Cc) {
        const int c = t >> 3, p = t & 7;
        const int bid = b * 256 + t;
        const float sc = scale_s[c];
        const float xm = (sc >= 0.f) ? ws[bid] : ws[NBINS + bid];
        pooled[p][c] = fmaxf(fmaf(sc, xm, shift_s[c]), 0.f);
    }
    __syncthreads();

    // ---- Stage C ----
    {
        const int h = t & 255, pq = t >> 8;
        const float4* wi = reinterpret_cast<const float4*>(w_ih) + h * (Cc / 4);
        float4 wiv[8];
#pragma unroll
        for (int e = 0; e < 8; ++e) wiv[e] = wi[e];
        const float bias = b_ih[h] + b_hh[h];
        float u0 = 0.f;
#pragma unroll
        for (int pp = 0; pp < 4; ++pp) {
            const int p = pq * 4 + pp;
            const float4* pl = reinterpret_cast<const float4*>(&pooled[p][0]);
            float a0 = bias, a1 = 0.f, a2 = 0.f, a3 = 0.f;
#pragma unroll
            for (int e = 0; e < 8; ++e) {
                float4 pv = pl[e];
                a0 = fmaf(pv.x, wiv[e].x, a0);
                a1 = fmaf(pv.y, wiv[e].y, a1);
                a2 = fmaf(pv.z, wiv[e].z, a2);
                a3 = fmaf(pv.w, wiv[e].w, a3);
            }
            const float uv = (a0 + a1) + (a2 + a3);
            u[p][h] = uv;
            if (pp == 0) u0 = uv;
        }
        if (pq == 0) hxs[0][(h >> 5) * 36 + (h & 31)] = fmaxf(u0, 0.f);
    }
    __syncthreads();

    // ---- Stage D ----
    int cur = 0;
    for (int step = 1; step < Pc; ++step) {
        float4 h4[8];
        const float4* hp = reinterpret_cast<const float4*>(&hxs[cur][kg * 36]);
#pragma unroll
        for (int e = 0; e < 8; ++e) h4[e] = hp[e];
        float acc[4];
#pragma unroll
        for (int r = 0; r < 4; ++r) {
            float a0 = 0.f, a1 = 0.f, a2 = 0.f, a3 = 0.f;
#pragma unroll
            for (int e = 0; e < 8; ++e) {
                float4 wv = w4[r][e], hv = h4[e];
                a0 = fmaf(hv.x, wv.x, a0);
                a1 = fmaf(hv.y, wv.y, a1);
                a2 = fmaf(hv.z, wv.z, a2);
                a3 = fmaf(hv.w, wv.w, a3);
            }
            acc[r] = (a0 + a1) + (a2 + a3);
        }
#pragma unroll
        for (int off = 1; off < 8; off <<= 1) {
#pragma unroll
            for (int r = 0; r < 4; ++r) acc[r] += __shfl_xor(acc[r], off);
        }
        if (kg == 0) {
#pragma unroll
            for (int r = 0; r < 4; ++r) {
                const int h = 4 * og + r;
                const float v = u[step][h] + acc[r];
                hxs[cur ^ 1][(h >> 5) * 36 + (h & 31)] = fmaxf(v, 0.f);
            }
        }
        __syncthreads();
        cur ^= 1;
    }

    // ---- Stage E ----
    {
        const int oi = t >> 2, seg = t & 3;
        const float4* wo = reinterpret_cast<const float4*>(w_out + oi * HIDc + seg * 64);
        float a0 = (seg == 0) ? b_out[oi] : 0.f, a1 = 0.f, a2 = 0.f, a3 = 0.f;
#pragma unroll
        for (int e = 0; e < 16; ++e) {
            const int k = seg * 64 + e * 4;
            const float4 hv = *reinterpret_cast<const float4*>(&hxs[1][(k >> 5) * 36 + (k & 31)]);
            const float4 wv = wo[e];
            a0 = fmaf(hv.x, wv.x, a0);
            a1 = fmaf(hv.y, wv.y, a1);
            a2 = fmaf(hv.z, wv.z, a2);
            a3 = fmaf(hv.w, wv.w, a3);
        }
        float s = (a0 + a1) + (a2 + a3);
        s += __shfl_xor(s, 1);
        s += __shfl_xor(s, 2);
        if (seg == 0) o[oi] = s;
    }
    __syncthreads();

    if (t < 64) {
        const float x0 = o[t], x1 = o[t + 64];
        float s = x0 + x1, ss = x0 * x0 + x1 * x1;
#pragma unroll
        for (int off = 1; off < 64; off <<= 1) {
            s  += __shfl_xor(s, off);
            ss += __shfl_xor(ss, off);
        }
        if (t == 0) { red2[0] = s; red2[1] = ss; }
    }
    __syncthreads();
    if (t < OUTc) {
        const float mu  = red2[0] * (1.0f / OUTc);
        const float var = red2[1] * (1.0f / OUTc) - mu * mu;
        const float rs  = rsqrtf(var + EPS);
        out[b * OUTc + t] = (o[t] - mu) * rs * ln_gamma[t] + ln_beta[t];
    }
}

extern "C" void kernel_launch(void* const* d_in, const int* in_sizes, int n_in,
                              void* d_out, int out_size, void* d_ws, size_t ws_size,
                              hipStream_t stream) {
    const float* x        = (const float*)d_in[0];
    const float* bn_gamma = (const float*)d_in[1];
    const float* bn_beta  = (const float*)d_in[2];
    const float* w_ih     = (const float*)d_in[3];
    const float* b_ih     = (const float*)d_in[4];
    const float* w_hh     = (const float*)d_in[5];
    const float* b_hh     = (const float*)d_in[6];
    const float* w_out    = (const float*)d_in[7];
    const float* b_out    = (const float*)d_in[8];
    const float* ln_gamma = (const float*)d_in[9];
    const float* ln_beta  = (const float*)d_in[10];
    float* out = (float*)d_out;
    float* ws  = (float*)d_ws;

    k1_stats<<<NBINS, 256, 0, stream>>>(x, ws);
    // ATTRIBUTION: k2 launched 3x (idempotent). Delta vs r8's 64.6 = 2 x k2_warm.
    k2_rnn<<<Bc, 512, 0, stream>>>(ws, bn_gamma, bn_beta, w_ih, b_ih, w_hh, b_hh,
                                   w_out, b_out, ln_gamma, ln_beta, out);
    k2_rnn<<<Bc, 512, 0, stream>>>(ws, bn_gamma, bn_beta, w_ih, b_ih, w_hh, b_hh,
                                   w_out, b_out, ln_gamma, ln_beta, out);
    k2_rnn<<<Bc, 512, 0, stream>>>(ws, bn_gamma, bn_beta, w_ih, b_ih, w_hh, b_hh,
                                   w_out, b_out, ln_gamma, ln_beta, out);
}

// Round 16
// 82.268 us; speedup vs baseline: 1.7108x; 1.2697x over previous
//
#include <hip/hip_runtime.h>
#include <math.h>

#define EPS 1e-5f

constexpr int Bc = 16, Cc = 32, Pc = 8, HIDc = 256, OUTc = 128;
constexpr int NBINS = 4096;
constexpr int NBLK = 256;                    // exactly 1 block per CU
constexpr float NPC_INV = 1.0f / 2097152.0f;
constexpr unsigned CNT_OFF_BYTES = 65536;    // counter in d_ws after the 16384 stat floats

typedef float fx4 __attribute__((ext_vector_type(4)));

// Dynamic LDS carve (floats) — spinner blocks only; 11588 floats = 45.3 KB (< 160 KB).
// [0,8192)      lds_wih (w_ih mirror, 32 KB)
// [8192,10240)  u[8][256]
// [10240,10880) hxs[2][320]   padded: word(k) = 20*(k>>4)+(k&15)
// [10880,11136) pooled[8][32]
// [11136,11264) pA[4][32]
// [11264,11392) pB[4][32]
// [11392,11424) scale_s | [11424,11456) shift_s
// [11456,11584) o[128]  | [11584,11586) red2
constexpr int SMEM_FLOATS = 11588;

// 256 blocks x 1024 threads. Phase 1: EVERY block streams 16 bins (one per wave,
// r8's proven NT pattern) -> full-device BW, no idle CUs. Each block then
// threadfence+atomicAdd. Blocks >=16 exit; blocks 0..15 issue their weight
// prefetch (overlaps the straggler tail), spin on the counter, run the RNN.
__global__ __launch_bounds__(1024, 4) void fused(const float* __restrict__ x,
                                                 float* __restrict__ ws,
                                                 unsigned* __restrict__ cnt,
                                                 const float* __restrict__ bn_gamma,
                                                 const float* __restrict__ bn_beta,
                                                 const float* __restrict__ w_ih,
                                                 const float* __restrict__ b_ih,
                                                 const float* __restrict__ w_hh,
                                                 const float* __restrict__ b_hh,
                                                 const float* __restrict__ w_out,
                                                 const float* __restrict__ b_out,
                                                 const float* __restrict__ ln_gamma,
                                                 const float* __restrict__ ln_beta,
                                                 float* __restrict__ out) {
    const int bid = blockIdx.x;
    const int t = threadIdx.x;                // 1024 threads = 16 waves
    const int wave = t >> 6, lane = t & 63;

    extern __shared__ __align__(16) float smem[];

    // ---------------- Phase 1: stream 16 bins (all 256 blocks) ----------------
    {
        const int bin = bid * 16 + wave;
        const fx4* px = reinterpret_cast<const fx4*>(x) + ((size_t)bin << 12) + lane;
        float vmax = -INFINITY, vmin = INFINITY, s = 0.f, ss = 0.f;
        for (int jj = 0; jj < 4; ++jj) {
#pragma unroll
            for (int j = 0; j < 16; ++j) {
                fx4 v = __builtin_nontemporal_load(&px[(jj * 16 + j) * 64]);
                vmax = fmaxf(vmax, fmaxf(fmaxf(v.x, v.y), fmaxf(v.z, v.w)));
                vmin = fminf(vmin, fminf(fminf(v.x, v.y), fminf(v.z, v.w)));
                s += (v.x + v.y) + (v.z + v.w);
                ss = fmaf(v.x, v.x, ss); ss = fmaf(v.y, v.y, ss);
                ss = fmaf(v.z, v.z, ss); ss = fmaf(v.w, v.w, ss);
            }
        }
#pragma unroll
        for (int off = 1; off < 64; off <<= 1) {
            vmax = fmaxf(vmax, __shfl_xor(vmax, off));
            vmin = fminf(vmin, __shfl_xor(vmin, off));
            s += __shfl_xor(s, off);
            ss += __shfl_xor(ss, off);
        }
        if (lane == 0) {
            ws[bin]             = vmax;
            ws[NBINS + bin]     = vmin;
            ws[2 * NBINS + bin] = s;
            ws[3 * NBINS + bin] = ss;
        }
    }
    __syncthreads();                 // drains all waves' stores
    if (t == 0) {
        __threadfence();             // make stores device-visible (cross-XCD)
        atomicAdd(cnt, 1u);
    }
    if (bid >= Bc) return;

    // ---------------- Blocks 0..15: prefetch weights, spin, RNN ----------------
    const int b = bid;
    float* lds_wih = smem;
    float* u       = smem + 8192;
    float* hxs     = smem + 10240;   // 2 x 320
    float* pooled  = smem + 10880;   // 8 x 32
    float* pA      = smem + 11136;   // 4 x 32
    float* pB      = smem + 11264;
    float* scale_s = smem + 11392;
    float* shift_s = smem + 11424;
    float* o       = smem + 11456;
    float* red2    = smem + 11584;

    // w_hh tile -> regs (issued now; flies during spin). Thread: rows 4g..4g+3, k16-slice.
    const int g = t >> 4, k16 = t & 15;
    fx4 w4[4][4];
#pragma unroll
    for (int r = 0; r < 4; ++r) {
        const fx4* wr = reinterpret_cast<const fx4*>(w_hh + (4 * g + r) * HIDc + 16 * k16);
#pragma unroll
        for (int e = 0; e < 4; ++e) w4[r][e] = wr[e];
    }
    // w_ih -> LDS mirror (32 KB)
    {
        const fx4* wi4 = reinterpret_cast<const fx4*>(w_ih);
        fx4* lwi = reinterpret_cast<fx4*>(lds_wih);
#pragma unroll
        for (int e = 0; e < 2; ++e) lwi[t * 2 + e] = wi4[t * 2 + e];
    }
    // scalars
    const int h_c = t & 255;
    const float bias_c = b_ih[h_c] + b_hh[h_c];
    const float bout_e = ((t & 7) == 0) ? b_out[t >> 3] : 0.f;
    float lng = 0.f, lnb = 0.f;
    if (t < OUTc) { lng = ln_gamma[t]; lnb = ln_beta[t]; }

    // ---- spin until all 256 blocks (incl. this one) have published ----
    if (t == 0) {
        for (int it = 0; it < 4000000; ++it) {
            if (atomicAdd(cnt, 0u) >= (unsigned)NBLK) break;
            __builtin_amdgcn_s_sleep(8);
        }
    }
    __syncthreads();
    __threadfence();   // acquire side

    // ---- Stage A: channel stats (coalesced; c invariant per thread) ----
    {
        const float* sums = ws + 2 * NBINS;
        const float* sqs  = ws + 3 * NBINS;
        float s = 0.f, ss = 0.f;
#pragma unroll
        for (int j = 0; j < 4; ++j) {
            s  += sums[t + 1024 * j];
            ss += sqs[t + 1024 * j];
        }
#pragma unroll
        for (int off = 1; off < 8; off <<= 1) {
            s  += __shfl_xor(s, off);
            ss += __shfl_xor(ss, off);
        }
        if ((t & 7) == 0) {
            const int c = (t >> 3) & 31, grp = t >> 8;
            pA[grp * 32 + c] = s;
            pB[grp * 32 + c] = ss;
        }
    }
    __syncthreads();
    if (t < Cc) {
        const float s  = pA[t] + pA[32 + t] + pA[64 + t] + pA[96 + t];
        const float ss = pB[t] + pB[32 + t] + pB[64 + t] + pB[96 + t];
        const float mean = s * NPC_INV;
        const float var  = ss * NPC_INV - mean * mean;
        const float sc   = bn_gamma[t] * rsqrtf(var + EPS);
        scale_s[t] = sc;
        shift_s[t] = bn_beta[t] - mean * sc;
    }
    __syncthreads();

    // ---- Stage B: pooled[p][c] ----
    if (t < Pc * Cc) {
        const int c = t >> 3, p = t & 7;
        const int bin = b * 256 + t;
        const float sc = scale_s[c];
        const float xm = (sc >= 0.f) ? ws[bin] : ws[NBINS + bin];
        pooled[p * 32 + c] = fmaxf(fmaf(sc, xm, shift_s[c]), 0.f);
    }
    __syncthreads();

    // ---- Stage C: u[p][h]; 4 p-groups x 2 p each; w_ih from LDS ----
    {
        const int h = h_c, pg = t >> 8;
        const fx4* lwi = reinterpret_cast<const fx4*>(lds_wih);
        fx4 wiv[8];
#pragma unroll
        for (int e = 0; e < 8; ++e) wiv[e] = lwi[h * 8 + e];
        float u0 = 0.f;
#pragma unroll
        for (int pp = 0; pp < 2; ++pp) {
            const int p = pg * 2 + pp;
            const fx4* pl = reinterpret_cast<const fx4*>(&pooled[p * 32]);
            float a0 = bias_c, a1 = 0.f, a2 = 0.f, a3 = 0.f;
#pragma unroll
            for (int e = 0; e < 8; ++e) {
                fx4 pv = pl[e];
                a0 = fmaf(pv.x, wiv[e].x, a0);
                a1 = fmaf(pv.y, wiv[e].y, a1);
                a2 = fmaf(pv.z, wiv[e].z, a2);
                a3 = fmaf(pv.w, wiv[e].w, a3);
            }
            const float uv = (a0 + a1) + (a2 + a3);
            u[p * 256 + h] = uv;
            if (pp == 0) u0 = uv;
        }
        if (pg == 0) hxs[20 * (h >> 4) + (h & 15)] = fmaxf(u0, 0.f);  // step 0
    }
    __syncthreads();

    // ---- Stage D: 7 recurrent steps; one barrier each; w4 resident ----
    int cur = 0;
    for (int step = 1; step < Pc; ++step) {
        const fx4* hp = reinterpret_cast<const fx4*>(&hxs[cur * 320 + 20 * k16]);
        fx4 h4[4];
#pragma unroll
        for (int e = 0; e < 4; ++e) h4[e] = hp[e];
        float acc[4];
#pragma unroll
        for (int r = 0; r < 4; ++r) {
            float a0 = 0.f, a1 = 0.f, a2 = 0.f, a3 = 0.f;
#pragma unroll
            for (int e = 0; e < 4; ++e) {
                fx4 wv = w4[r][e], hv = h4[e];
                a0 = fmaf(hv.x, wv.x, a0);
                a1 = fmaf(hv.y, wv.y, a1);
                a2 = fmaf(hv.z, wv.z, a2);
                a3 = fmaf(hv.w, wv.w, a3);
            }
            acc[r] = (a0 + a1) + (a2 + a3);
        }
#pragma unroll
        for (int off = 1; off < 16; off <<= 1) {
#pragma unroll
            for (int r = 0; r < 4; ++r) acc[r] += __shfl_xor(acc[r], off);
        }
        if (k16 == 0) {
#pragma unroll
            for (int r = 0; r < 4; ++r) {
                const int h = 4 * g + r;
                const float v = u[step * 256 + h] + acc[r];
                hxs[(cur ^ 1) * 320 + 20 * (h >> 4) + (h & 15)] = fmaxf(v, 0.f);
            }
        }
        __syncthreads();
        cur ^= 1;
    }
    // final hx in hxs[1]

    // ---- Stage E: out-proj; w_out direct from global (TLP-covered) ----
    {
        const int oi = t >> 3, seg = t & 7;
        const fx4* wo4 = reinterpret_cast<const fx4*>(w_out);
        float a0 = bout_e, a1 = 0.f, a2 = 0.f, a3 = 0.f;
#pragma unroll
        for (int e = 0; e < 8; ++e) {
            const int k = seg * 32 + e * 4;
            const fx4 hv = *reinterpret_cast<const fx4*>(&hxs[320 + 20 * (k >> 4) + (k & 15)]);
            const fx4 wv = wo4[oi * 64 + seg * 8 + e];
            a0 = fmaf(hv.x, wv.x, a0);
            a1 = fmaf(hv.y, wv.y, a1);
            a2 = fmaf(hv.z, wv.z, a2);
            a3 = fmaf(hv.w, wv.w, a3);
        }
        float s = (a0 + a1) + (a2 + a3);
        s += __shfl_xor(s, 1);
        s += __shfl_xor(s, 2);
        s += __shfl_xor(s, 4);
        if (seg == 0) o[oi] = s;
    }
    __syncthreads();

    // ---- LayerNorm over 128 ----
    if (t < 64) {
        const float x0 = o[t], x1 = o[t + 64];
        float s = x0 + x1, ss = x0 * x0 + x1 * x1;
#pragma unroll
        for (int off = 1; off < 64; off <<= 1) {
            s  += __shfl_xor(s, off);
            ss += __shfl_xor(ss, off);
        }
        if (t == 0) { red2[0] = s; red2[1] = ss; }
    }
    __syncthreads();
    if (t < OUTc) {
        const float mu  = red2[0] * (1.0f / OUTc);
        const float var = red2[1] * (1.0f / OUTc) - mu * mu;
        const float rs  = rsqrtf(var + EPS);
        out[b * OUTc + t] = (o[t] - mu) * rs * lng + lnb;
    }
}

extern "C" void kernel_launch(void* const* d_in, const int* in_sizes, int n_in,
                              void* d_out, int out_size, void* d_ws, size_t ws_size,
                              hipStream_t stream) {
    const float* x        = (const float*)d_in[0];
    const float* bn_gamma = (const float*)d_in[1];
    const float* bn_beta  = (const float*)d_in[2];
    const float* w_ih     = (const float*)d_in[3];
    const float* b_ih     = (const float*)d_in[4];
    const float* w_hh     = (const float*)d_in[5];
    const float* b_hh     = (const float*)d_in[6];
    const float* w_out    = (const float*)d_in[7];
    const float* b_out    = (const float*)d_in[8];
    const float* ln_gamma = (const float*)d_in[9];
    const float* ln_beta  = (const float*)d_in[10];
    float* out = (float*)d_out;
    float* ws  = (float*)d_ws;
    unsigned* cnt = (unsigned*)((char*)d_ws + CNT_OFF_BYTES);

    hipMemsetAsync(cnt, 0, 4, stream);   // per-launch counter reset (graph-capturable)
    fused<<<NBLK, 1024, SMEM_FLOATS * sizeof(float), stream>>>(
        x, ws, cnt, bn_gamma, bn_beta, w_ih, b_ih, w_hh, b_hh,
        w_out, b_out, ln_gamma, ln_beta, out);
}

// Round 17
// 66.403 us; speedup vs baseline: 2.1195x; 1.2389x over previous
//
#include <hip/hip_runtime.h>
#include <math.h>

#define EPS 1e-5f

constexpr int Bc = 16, Cc = 32, Pc = 8, HIDc = 256, OUTc = 128;
constexpr int NBINS = 4096;
constexpr float NPC_INV = 1.0f / 2097152.0f;

typedef float fx4 __attribute__((ext_vector_type(4)));

// ws layout (floats): [0,4096) max | [4096,8192) min | [8192,12288) sum | [12288,16384) sumsq

// ---------------- Kernel 1: byte-identical to r8 (41 us = 6.5 TB/s, at read ceiling) ----------------
__global__ __launch_bounds__(256) void k1_stats(const float* __restrict__ x,
                                                float* __restrict__ ws) {
    const int bid = blockIdx.x;
    const int t = threadIdx.x;
    const fx4* px = reinterpret_cast<const fx4*>(x) + ((size_t)bid << 12);

    float vmax = -INFINITY, vmin = INFINITY, s = 0.f, ss = 0.f;
#pragma unroll
    for (int j = 0; j < 16; ++j) {
        fx4 v = __builtin_nontemporal_load(&px[j * 256 + t]);
        vmax = fmaxf(vmax, fmaxf(fmaxf(v.x, v.y), fmaxf(v.z, v.w)));
        vmin = fminf(vmin, fminf(fminf(v.x, v.y), fminf(v.z, v.w)));
        s += (v.x + v.y) + (v.z + v.w);
        ss = fmaf(v.x, v.x, ss); ss = fmaf(v.y, v.y, ss);
        ss = fmaf(v.z, v.z, ss); ss = fmaf(v.w, v.w, ss);
    }
#pragma unroll
    for (int off = 1; off < 64; off <<= 1) {
        vmax = fmaxf(vmax, __shfl_xor(vmax, off));
        vmin = fminf(vmin, __shfl_xor(vmin, off));
        s += __shfl_xor(s, off);
        ss += __shfl_xor(ss, off);
    }
    __shared__ float r[4][4];
    const int wid = t >> 6;
    if ((t & 63) == 0) { r[wid][0] = vmax; r[wid][1] = vmin; r[wid][2] = s; r[wid][3] = ss; }
    __syncthreads();
    if (t == 0) {
        vmax = fmaxf(fmaxf(r[0][0], r[1][0]), fmaxf(r[2][0], r[3][0]));
        vmin = fminf(fminf(r[0][1], r[1][1]), fminf(r[2][1], r[3][1]));
        s  = (r[0][2] + r[1][2]) + (r[2][2] + r[3][2]);
        ss = (r[0][3] + r[1][3]) + (r[2][3] + r[3][3]);
        ws[bid]             = vmax;
        ws[NBINS + bid]     = vmin;
        ws[2 * NBINS + bid] = s;
        ws[3 * NBINS + bid] = ss;
    }
}

// ---------------- Kernel 2: r8 structure + ALL global loads issued in one top burst ----------------
// w_hh tile (128 VGPR) + w_out quarter-rows (64 VGPR) + stage-B stats + biases + LN params
// all in flight before stage A; the single vmcnt(0) drain at barrier-1 pays ONE latency.
// Stage E runs entirely from registers. VGPR peak ~250 (launch_bounds(512,2) cap 256).
__global__ __launch_bounds__(512, 2) void k2_rnn(const float* __restrict__ ws,
                                                 const float* __restrict__ bn_gamma,
                                                 const float* __restrict__ bn_beta,
                                                 const float* __restrict__ w_ih,
                                                 const float* __restrict__ b_ih,
                                                 const float* __restrict__ w_hh,
                                                 const float* __restrict__ b_hh,
                                                 const float* __restrict__ w_out,
                                                 const float* __restrict__ b_out,
                                                 const float* __restrict__ ln_gamma,
                                                 const float* __restrict__ ln_beta,
                                                 float* __restrict__ out) {
    const int b = blockIdx.x;
    const int t = threadIdx.x;                 // 512 threads
    const int og = t >> 3, kg = t & 7;

    __shared__ float scale_s[Cc], shift_s[Cc];
    __shared__ float pA[2][Cc], pB[2][Cc];
    __shared__ __align__(16) float pooled[Pc][Cc];
    __shared__ __align__(16) float u[Pc][HIDc];
    __shared__ __align__(16) float hxs[2][288];   // word(k) = 36*(k>>5) + (k&31)
    __shared__ __align__(16) float o[OUTc];
    __shared__ float red2[2];

    // ===== TOP BURST: issue every global load now =====
    float4 w4[4][8];                                   // w_hh tile: rows 4og..4og+3, k in [32kg,32kg+32)
#pragma unroll
    for (int r = 0; r < 4; ++r) {
        const float4* wr = reinterpret_cast<const float4*>(w_hh + (4 * og + r) * HIDc + 32 * kg);
#pragma unroll
        for (int e = 0; e < 8; ++e) w4[r][e] = wr[e];
    }
    float4 wo[16];                                     // w_out: oi = t>>2, seg = t&3, 64-k slice
    {
        const float4* wop = reinterpret_cast<const float4*>(w_out + (t >> 2) * HIDc + (t & 3) * 64);
#pragma unroll
        for (int e = 0; e < 16; ++e) wo[e] = wop[e];
    }
    float xmaxv = 0.f, xminv = 0.f;                    // stage-B stats (bin = b*256 + t)
    if (t < 256) { xmaxv = ws[b * 256 + t]; xminv = ws[NBINS + b * 256 + t]; }
    const int h_c = t & 255;
    const float bias_c = b_ih[h_c] + b_hh[h_c];
    const float bout_e = ((t & 3) == 0) ? b_out[t >> 2] : 0.f;
    float lng = 0.f, lnb = 0.f;
    if (t < OUTc) { lng = ln_gamma[t]; lnb = ln_beta[t]; }

    // ---- Stage A: channel stats (coalesced; c = (t>>3)&31 invariant) ----
    {
        const float* sums = ws + 2 * NBINS;
        const float* sqs  = ws + 3 * NBINS;
        float s = 0.f, ss = 0.f;
#pragma unroll
        for (int j = 0; j < 8; ++j) {
            s  += sums[t + 512 * j];
            ss += sqs[t + 512 * j];
        }
#pragma unroll
        for (int off = 1; off < 8; off <<= 1) {
            s  += __shfl_xor(s, off);
            ss += __shfl_xor(ss, off);
        }
        if ((t & 7) == 0) {
            pA[t >> 8][(t >> 3) & 31] = s;
            pB[t >> 8][(t >> 3) & 31] = ss;
        }
    }
    __syncthreads();   // B1: single drain point for the whole burst
    if (t < Cc) {
        const float s = pA[0][t] + pA[1][t], ss = pB[0][t] + pB[1][t];
        const float mean = s * NPC_INV;
        const float var  = ss * NPC_INV - mean * mean;
        const float sc   = bn_gamma[t] * rsqrtf(var + EPS);
        scale_s[t] = sc;
        shift_s[t] = bn_beta[t] - mean * sc;
    }
    __syncthreads();   // B2

    // ---- Stage B: pooled from prefetched stats ----
    if (t < 256) {
        const int c = t >> 3;
        const float sc = scale_s[c];
        const float xm = (sc >= 0.f) ? xmaxv : xminv;
        pooled[t & 7][c] = fmaxf(fmaf(sc, xm, shift_s[c]), 0.f);
    }
    __syncthreads();   // B3

    // ---- Stage C: u[p][h]; w_ih from global (8-wave TLP covers it) ----
    {
        const int h = h_c, pg = t >> 8;
        const float4* wi = reinterpret_cast<const float4*>(w_ih) + h * (Cc / 4);
        float4 wiv[8];
#pragma unroll
        for (int e = 0; e < 8; ++e) wiv[e] = wi[e];
        float u0 = 0.f;
#pragma unroll
        for (int pp = 0; pp < 4; ++pp) {
            const int p = pg * 4 + pp;
            const float4* pl = reinterpret_cast<const float4*>(&pooled[p][0]);
            float a0 = bias_c, a1 = 0.f, a2 = 0.f, a3 = 0.f;
#pragma unroll
            for (int e = 0; e < 8; ++e) {
                float4 pv = pl[e];
                a0 = fmaf(pv.x, wiv[e].x, a0);
                a1 = fmaf(pv.y, wiv[e].y, a1);
                a2 = fmaf(pv.z, wiv[e].z, a2);
                a3 = fmaf(pv.w, wiv[e].w, a3);
            }
            const float uv = (a0 + a1) + (a2 + a3);
            u[p][h] = uv;
            if (pp == 0) u0 = uv;
        }
        if (pg == 0) hxs[0][36 * (h >> 5) + (h & 31)] = fmaxf(u0, 0.f);  // step 0
    }
    __syncthreads();   // B4

    // ---- Stage D: 7 recurrent steps, one barrier each (w4 resident) ----
    int cur = 0;
    for (int step = 1; step < Pc; ++step) {
        float4 h4[8];
        const float4* hp = reinterpret_cast<const float4*>(&hxs[cur][kg * 36]);
#pragma unroll
        for (int e = 0; e < 8; ++e) h4[e] = hp[e];
        float acc[4];
#pragma unroll
        for (int r = 0; r < 4; ++r) {
            float a0 = 0.f, a1 = 0.f, a2 = 0.f, a3 = 0.f;
#pragma unroll
            for (int e = 0; e < 8; ++e) {
                float4 wv = w4[r][e], hv = h4[e];
                a0 = fmaf(hv.x, wv.x, a0);
                a1 = fmaf(hv.y, wv.y, a1);
                a2 = fmaf(hv.z, wv.z, a2);
                a3 = fmaf(hv.w, wv.w, a3);
            }
            acc[r] = (a0 + a1) + (a2 + a3);
        }
#pragma unroll
        for (int off = 1; off < 8; off <<= 1) {
#pragma unroll
            for (int r = 0; r < 4; ++r) acc[r] += __shfl_xor(acc[r], off);
        }
        if (kg == 0) {
#pragma unroll
            for (int r = 0; r < 4; ++r) {
                const int h = 4 * og + r;
                const float v = u[step][h] + acc[r];
                hxs[cur ^ 1][36 * (h >> 5) + (h & 31)] = fmaxf(v, 0.f);
            }
        }
        __syncthreads();
        cur ^= 1;
    }
    // final hx in hxs[1]

    // ---- Stage E: out-proj entirely from registers (wo) ----
    {
        const int seg = t & 3;
        float a0 = bout_e, a1 = 0.f, a2 = 0.f, a3 = 0.f;
#pragma unroll
        for (int e = 0; e < 16; ++e) {
            const int k = seg * 64 + e * 4;
            const float4 hv = *reinterpret_cast<const float4*>(&hxs[1][36 * (k >> 5) + (k & 31)]);
            const float4 wv = wo[e];
            a0 = fmaf(hv.x, wv.x, a0);
            a1 = fmaf(hv.y, wv.y, a1);
            a2 = fmaf(hv.z, wv.z, a2);
            a3 = fmaf(hv.w, wv.w, a3);
        }
        float s = (a0 + a1) + (a2 + a3);
        s += __shfl_xor(s, 1);
        s += __shfl_xor(s, 2);
        if (seg == 0) o[t >> 2] = s;
    }
    __syncthreads();

    // ---- LayerNorm over 128 ----
    if (t < 64) {
        const float x0 = o[t], x1 = o[t + 64];
        float s = x0 + x1, ss = x0 * x0 + x1 * x1;
#pragma unroll
        for (int off = 1; off < 64; off <<= 1) {
            s  += __shfl_xor(s, off);
            ss += __shfl_xor(ss, off);
        }
        if (t == 0) { red2[0] = s; red2[1] = ss; }
    }
    __syncthreads();
    if (t < OUTc) {
        const float mu  = red2[0] * (1.0f / OUTc);
        const float var = red2[1] * (1.0f / OUTc) - mu * mu;
        const float rs  = rsqrtf(var + EPS);
        out[b * OUTc + t] = (o[t] - mu) * rs * lng + lnb;
    }
}

extern "C" void kernel_launch(void* const* d_in, const int* in_sizes, int n_in,
                              void* d_out, int out_size, void* d_ws, size_t ws_size,
                              hipStream_t stream) {
    const float* x        = (const float*)d_in[0];
    const float* bn_gamma = (const float*)d_in[1];
    const float* bn_beta  = (const float*)d_in[2];
    const float* w_ih     = (const float*)d_in[3];
    const float* b_ih     = (const float*)d_in[4];
    const float* w_hh     = (const float*)d_in[5];
    const float* b_hh     = (const float*)d_in[6];
    const float* w_out    = (const float*)d_in[7];
    const float* b_out    = (const float*)d_in[8];
    const float* ln_gamma = (const float*)d_in[9];
    const float* ln_beta  = (const float*)d_in[10];
    float* out = (float*)d_out;
    float* ws  = (float*)d_ws;

    k1_stats<<<NBINS, 256, 0, stream>>>(x, ws);
    k2_rnn<<<Bc, 512, 0, stream>>>(ws, bn_gamma, bn_beta, w_ih, b_ih, w_hh, b_hh,
                                   w_out, b_out, ln_gamma, ln_beta, out);
}

// Round 18
// 60.894 us; speedup vs baseline: 2.3113x; 1.0905x over previous
//
#include <hip/hip_runtime.h>
#include <math.h>
#include <stdint.h>

#define EPS 1e-5f

constexpr int Bc = 16, Cc = 32, Pc = 8, HIDc = 256, OUTc = 128;
constexpr int NBINS = 4096;
constexpr float NPC_INV = 1.0f / 2097152.0f;

// d_ws byte layout: [0,65536) stats (16384 f32) | [65536,196608) w_hh bf16 (65536 u16)
//                   | [196608,262144) w_out bf16 (32768 u16).  Requires ws_size >= 256 KB.
constexpr size_t WHH16_BYTE  = 65536;
constexpr size_t WOUT16_BYTE = 196608;

typedef float fx4 __attribute__((ext_vector_type(4)));

__device__ inline uint32_t bf16_rne(float f) {
    uint32_t u = __float_as_uint(f);
    return (u + 0x7fffu + ((u >> 16) & 1u)) >> 16;   // round-nearest-even
}

// ---------------- Kernel 1: r8's streaming body + weight->bf16 fold-in ----------------
// Blocks 0..127 convert a 512-elem slice of w_hh; blocks 128..191 a slice of w_out
// (first-dispatched blocks, ~0.3 us each, done long before k1's tail). Then all 4096
// blocks stream their bin exactly as r8 (41 us = 6.5 TB/s, at read ceiling).
__global__ __launch_bounds__(256) void k1_stats(const float* __restrict__ x,
                                                float* __restrict__ ws,
                                                const float* __restrict__ w_hh,
                                                const float* __restrict__ w_out) {
    const int bid = blockIdx.x;
    const int t = threadIdx.x;

    if (bid < 192) {
        const bool hh = bid < 128;
        const float* src = hh ? w_hh : w_out;
        uint32_t* dst = (uint32_t*)((char*)ws + (hh ? WHH16_BYTE : WOUT16_BYTE));
        const int i = (hh ? bid : bid - 128) * 512 + t * 2;
        const float a = src[i], b = src[i + 1];
        dst[i >> 1] = bf16_rne(a) | (bf16_rne(b) << 16);
    }

    const fx4* px = reinterpret_cast<const fx4*>(x) + ((size_t)bid << 12);

    float vmax = -INFINITY, vmin = INFINITY, s = 0.f, ss = 0.f;
#pragma unroll
    for (int j = 0; j < 16; ++j) {
        fx4 v = __builtin_nontemporal_load(&px[j * 256 + t]);
        vmax = fmaxf(vmax, fmaxf(fmaxf(v.x, v.y), fmaxf(v.z, v.w)));
        vmin = fminf(vmin, fminf(fminf(v.x, v.y), fminf(v.z, v.w)));
        s += (v.x + v.y) + (v.z + v.w);
        ss = fmaf(v.x, v.x, ss); ss = fmaf(v.y, v.y, ss);
        ss = fmaf(v.z, v.z, ss); ss = fmaf(v.w, v.w, ss);
    }
#pragma unroll
    for (int off = 1; off < 64; off <<= 1) {
        vmax = fmaxf(vmax, __shfl_xor(vmax, off));
        vmin = fminf(vmin, __shfl_xor(vmin, off));
        s += __shfl_xor(s, off);
        ss += __shfl_xor(ss, off);
    }
    __shared__ float r[4][4];
    const int wid = t >> 6;
    if ((t & 63) == 0) { r[wid][0] = vmax; r[wid][1] = vmin; r[wid][2] = s; r[wid][3] = ss; }
    __syncthreads();
    if (t == 0) {
        vmax = fmaxf(fmaxf(r[0][0], r[1][0]), fmaxf(r[2][0], r[3][0]));
        vmin = fminf(fminf(r[0][1], r[1][1]), fminf(r[2][1], r[3][1]));
        s  = (r[0][2] + r[1][2]) + (r[2][2] + r[3][2]);
        ss = (r[0][3] + r[1][3]) + (r[2][3] + r[3][3]);
        ws[bid]             = vmax;
        ws[NBINS + bid]     = vmin;
        ws[2 * NBINS + bid] = s;
        ws[3 * NBINS + bid] = ss;
    }
}

// ---------------- Kernel 2: r8 structure verbatim; weights fetched as bf16 (half bytes) ----------------
__global__ __launch_bounds__(512, 2) void k2_rnn(const float* __restrict__ ws,
                                                 const float* __restrict__ bn_gamma,
                                                 const float* __restrict__ bn_beta,
                                                 const float* __restrict__ w_ih,
                                                 const float* __restrict__ b_ih,
                                                 const float* __restrict__ b_hh,
                                                 const float* __restrict__ b_out,
                                                 const float* __restrict__ ln_gamma,
                                                 const float* __restrict__ ln_beta,
                                                 float* __restrict__ out) {
    const int b = blockIdx.x;
    const int t = threadIdx.x;                 // 512 threads
    const int og = t >> 3, kg = t & 7;

    const uint32_t* whh16  = (const uint32_t*)((const char*)ws + WHH16_BYTE);
    const uint32_t* wout16 = (const uint32_t*)((const char*)ws + WOUT16_BYTE);

    __shared__ float scale_s[Cc], shift_s[Cc];
    __shared__ float pA[2][Cc], pB[2][Cc];
    __shared__ __align__(16) float pooled[Pc][Cc];
    __shared__ __align__(16) float u[Pc][HIDc];
    __shared__ __align__(16) float hxs[2][288];   // word(k) = 36*(k>>5) + (k&31)
    __shared__ __align__(16) float o[OUTc];
    __shared__ float red2[2];

    // ---- Stage A: channel stats (coalesced; c = (t>>3)&31 invariant) ----
    {
        const float* sums = ws + 2 * NBINS;
        const float* sqs  = ws + 3 * NBINS;
        float s = 0.f, ss = 0.f;
#pragma unroll
        for (int j = 0; j < 8; ++j) {
            s  += sums[t + 512 * j];
            ss += sqs[t + 512 * j];
        }
#pragma unroll
        for (int off = 1; off < 8; off <<= 1) {
            s  += __shfl_xor(s, off);
            ss += __shfl_xor(ss, off);
        }
        if ((t & 7) == 0) {
            pA[t >> 8][(t >> 3) & 31] = s;
            pB[t >> 8][(t >> 3) & 31] = ss;
        }
    }

    // ---- Issue packed w_hh tile loads (16 uint4/thread = 192 KB/block incl w_out later) ----
    uint32_t wpk[4][16];
#pragma unroll
    for (int r = 0; r < 4; ++r) {
        const uint4* wrow = reinterpret_cast<const uint4*>(whh16 + (4 * og + r) * 128 + 16 * kg);
#pragma unroll
        for (int q = 0; q < 4; ++q) {
            uint4 v = wrow[q];
            wpk[r][4 * q + 0] = v.x; wpk[r][4 * q + 1] = v.y;
            wpk[r][4 * q + 2] = v.z; wpk[r][4 * q + 3] = v.w;
        }
    }

    __syncthreads();   // B1: drains stage-A reads + packed weight loads

    // ---- Unpack bf16 -> f32 registers in the t<32 dead window ----
    float4 w4[4][8];
#pragma unroll
    for (int r = 0; r < 4; ++r) {
#pragma unroll
        for (int e = 0; e < 8; ++e) {
            const uint32_t u0 = wpk[r][2 * e], u1 = wpk[r][2 * e + 1];
            w4[r][e].x = __uint_as_float(u0 << 16);
            w4[r][e].y = __uint_as_float(u0 & 0xFFFF0000u);
            w4[r][e].z = __uint_as_float(u1 << 16);
            w4[r][e].w = __uint_as_float(u1 & 0xFFFF0000u);
        }
    }
    if (t < Cc) {
        const float s = pA[0][t] + pA[1][t], ss = pB[0][t] + pB[1][t];
        const float mean = s * NPC_INV;
        const float var  = ss * NPC_INV - mean * mean;
        const float sc   = bn_gamma[t] * rsqrtf(var + EPS);
        scale_s[t] = sc;
        shift_s[t] = bn_beta[t] - mean * sc;
    }
    __syncthreads();   // B2

    // ---- Stage B: pooled (bin = b*256 + t, coalesced) ----
    if (t < 256) {
        const int c = t >> 3;
        const int bin = b * 256 + t;
        const float sc = scale_s[c];
        const float xm = (sc >= 0.f) ? ws[bin] : ws[NBINS + bin];
        pooled[t & 7][c] = fmaxf(fmaf(sc, xm, shift_s[c]), 0.f);
    }
    __syncthreads();   // B3

    // ---- Stage C: u[p][h]; w_ih from global f32 (8-wave TLP covers it) ----
    {
        const int h = t & 255, pg = t >> 8;
        const float4* wi = reinterpret_cast<const float4*>(w_ih) + h * (Cc / 4);
        float4 wiv[8];
#pragma unroll
        for (int e = 0; e < 8; ++e) wiv[e] = wi[e];
        const float bias = b_ih[h] + b_hh[h];
        float u0 = 0.f;
#pragma unroll
        for (int pp = 0; pp < 4; ++pp) {
            const int p = pg * 4 + pp;
            const float4* pl = reinterpret_cast<const float4*>(&pooled[p][0]);
            float a0 = bias, a1 = 0.f, a2 = 0.f, a3 = 0.f;
#pragma unroll
            for (int e = 0; e < 8; ++e) {
                float4 pv = pl[e];
                a0 = fmaf(pv.x, wiv[e].x, a0);
                a1 = fmaf(pv.y, wiv[e].y, a1);
                a2 = fmaf(pv.z, wiv[e].z, a2);
                a3 = fmaf(pv.w, wiv[e].w, a3);
            }
            const float uv = (a0 + a1) + (a2 + a3);
            u[p][h] = uv;
            if (pp == 0) u0 = uv;
        }
        if (pg == 0) hxs[0][36 * (h >> 5) + (h & 31)] = fmaxf(u0, 0.f);  // step 0
    }
    __syncthreads();   // B4

    // ---- Stage D: 7 recurrent steps, one barrier each (w4 resident in f32 regs) ----
    int cur = 0;
    for (int step = 1; step < Pc; ++step) {
        float4 h4[8];
        const float4* hp = reinterpret_cast<const float4*>(&hxs[cur][kg * 36]);
#pragma unroll
        for (int e = 0; e < 8; ++e) h4[e] = hp[e];
        float acc[4];
#pragma unroll
        for (int r = 0; r < 4; ++r) {
            float a0 = 0.f, a1 = 0.f, a2 = 0.f, a3 = 0.f;
#pragma unroll
            for (int e = 0; e < 8; ++e) {
                float4 wv = w4[r][e], hv = h4[e];
                a0 = fmaf(hv.x, wv.x, a0);
                a1 = fmaf(hv.y, wv.y, a1);
                a2 = fmaf(hv.z, wv.z, a2);
                a3 = fmaf(hv.w, wv.w, a3);
            }
            acc[r] = (a0 + a1) + (a2 + a3);
        }
#pragma unroll
        for (int off = 1; off < 8; off <<= 1) {
#pragma unroll
            for (int r = 0; r < 4; ++r) acc[r] += __shfl_xor(acc[r], off);
        }
        if (kg == 0) {
#pragma unroll
            for (int r = 0; r < 4; ++r) {
                const int h = 4 * og + r;
                const float v = u[step][h] + acc[r];
                hxs[cur ^ 1][36 * (h >> 5) + (h & 31)] = fmaxf(v, 0.f);
            }
        }
        __syncthreads();
        cur ^= 1;
    }
    // final hx in hxs[1]

    // ---- Stage E: out-proj; w_out read as bf16 from ws (64 KB/block), unpack inline ----
    {
        const int oi = t >> 2, seg = t & 3;
        const uint4* wop = reinterpret_cast<const uint4*>(wout16) + oi * 32 + seg * 8;
        float a0 = ((t & 3) == 0) ? b_out[oi] : 0.f, a1 = 0.f, a2 = 0.f, a3 = 0.f;
#pragma unroll
        for (int e = 0; e < 8; ++e) {
            const uint4 pk = wop[e];
            const int k = seg * 64 + e * 8;
            const int base = 36 * (k >> 5) + (k & 31);
            const float4 hv0 = *reinterpret_cast<const float4*>(&hxs[1][base]);
            const float4 hv1 = *reinterpret_cast<const float4*>(&hxs[1][base + 4]);
            a0 = fmaf(hv0.x, __uint_as_float(pk.x << 16), a0);
            a1 = fmaf(hv0.y, __uint_as_float(pk.x & 0xFFFF0000u), a1);
            a2 = fmaf(hv0.z, __uint_as_float(pk.y << 16), a2);
            a3 = fmaf(hv0.w, __uint_as_float(pk.y & 0xFFFF0000u), a3);
            a0 = fmaf(hv1.x, __uint_as_float(pk.z << 16), a0);
            a1 = fmaf(hv1.y, __uint_as_float(pk.z & 0xFFFF0000u), a1);
            a2 = fmaf(hv1.z, __uint_as_float(pk.w << 16), a2);
            a3 = fmaf(hv1.w, __uint_as_float(pk.w & 0xFFFF0000u), a3);
        }
        float s = (a0 + a1) + (a2 + a3);
        s += __shfl_xor(s, 1);
        s += __shfl_xor(s, 2);
        if (seg == 0) o[oi] = s;
    }
    __syncthreads();

    // ---- LayerNorm over 128 ----
    if (t < 64) {
        const float x0 = o[t], x1 = o[t + 64];
        float s = x0 + x1, ss = x0 * x0 + x1 * x1;
#pragma unroll
        for (int off = 1; off < 64; off <<= 1) {
            s  += __shfl_xor(s, off);
            ss += __shfl_xor(ss, off);
        }
        if (t == 0) { red2[0] = s; red2[1] = ss; }
    }
    __syncthreads();
    if (t < OUTc) {
        const float mu  = red2[0] * (1.0f / OUTc);
        const float var = red2[1] * (1.0f / OUTc) - mu * mu;
        const float rs  = rsqrtf(var + EPS);
        out[b * OUTc + t] = (o[t] - mu) * rs * ln_gamma[t] + ln_beta[t];
    }
}

extern "C" void kernel_launch(void* const* d_in, const int* in_sizes, int n_in,
                              void* d_out, int out_size, void* d_ws, size_t ws_size,
                              hipStream_t stream) {
    const float* x        = (const float*)d_in[0];
    const float* bn_gamma = (const float*)d_in[1];
    const float* bn_beta  = (const float*)d_in[2];
    const float* w_ih     = (const float*)d_in[3];
    const float* b_ih     = (const float*)d_in[4];
    const float* w_hh     = (const float*)d_in[5];
    const float* b_hh     = (const float*)d_in[6];
    const float* w_out    = (const float*)d_in[7];
    const float* b_out    = (const float*)d_in[8];
    const float* ln_gamma = (const float*)d_in[9];
    const float* ln_beta  = (const float*)d_in[10];
    float* out = (float*)d_out;
    float* ws  = (float*)d_ws;

    k1_stats<<<NBINS, 256, 0, stream>>>(x, ws, w_hh, w_out);
    k2_rnn<<<Bc, 512, 0, stream>>>(ws, bn_gamma, bn_beta, w_ih, b_ih, b_hh,
                                   b_out, ln_gamma, ln_beta, out);
}